// Round 7
// baseline (364.921 us; speedup 1.0000x reference)
//
#include <hip/hip_runtime.h>
#include <hip/hip_bf16.h>

// GAT: N=50000, E=850000, HID=128, HEADS=8, DH=16, LAYERS=2.
// R10: (1) monotonic rowptr restored WITHOUT extra launches: histpack builds a
//      per-256-node chunk histogram; each scan block derives its base by
//      summing chunkdeg[0..cb) (fixes R8/R9's +4us/aggregate from permuted CSR
//      layout). (2) gemm_body stages Wh+Wl (64KB) in LDS once per block —
//      cuts ~820MB/GEMM of L2 B-reads to ~50MB (the hidden ~80us).

typedef __attribute__((ext_vector_type(8))) short short8;   // 8 bf16 = 4 VGPRs
typedef __attribute__((ext_vector_type(4))) float floatx4;
typedef __attribute__((ext_vector_type(2))) float floatx2;

__device__ __forceinline__ unsigned f2u(float f) { return __float_as_uint(f); }
__device__ __forceinline__ float u2f(unsigned u) { return __uint_as_float(u); }
__device__ __forceinline__ unsigned short f2bf_rne(float x) {
    unsigned u = f2u(x);
    unsigned r = (u + 0x7FFF + ((u >> 16) & 1)) >> 16;
    return (unsigned short)r;
}

// ---------------- CSR build ----------------

// blocks [0, EB): histogram + rank capture + chunk histogram (256 nodes/chunk).
// blocks [EB, EB+24): weight pack.
__global__ void histpack_kernel(const int* __restrict__ row, int* __restrict__ deg,
                                int* __restrict__ chunkdeg, int* __restrict__ rank,
                                int E, int EB, int NCH,
                                const float* __restrict__ encW,
                                const float* __restrict__ Wstack,
                                short8* __restrict__ Wh, short8* __restrict__ Wl) {
    int b = blockIdx.x;
    if (b < EB) {
        __shared__ int ch[256];
        int t = threadIdx.x;
        ch[t] = 0;
        __syncthreads();
        int e = b * 256 + t;
        if (e < E) {
            int r = row[e];
            rank[e] = atomicAdd(&deg[r], 1);
            atomicAdd(&ch[r >> 8], 1);
        }
        __syncthreads();
        if (t < NCH && ch[t] > 0) atomicAdd(&chunkdeg[t], ch[t]);
        return;
    }
    int idx = (b - EB) * 256 + threadIdx.x;
    if (idx >= 3 * 2048) return;
    int mat = idx >> 11;
    int r = idx & 2047;
    int lane = r & 63;
    int tile = r >> 6;            // ct*4 + kt
    int ct = tile >> 2, kt = tile & 3;
    int ncol = ct * 16 + (lane & 15);
    int k0 = kt * 32 + ((lane >> 4) * 8);
    short8 hv, lv;
#pragma unroll
    for (int j = 0; j < 8; ++j) {
        int k = k0 + j;
        float w = (mat == 0)
            ? encW[k * 128 + ncol]
            : Wstack[(mat - 1) * 16384 + (ncol >> 4) * 2048 + k * 16 + (ncol & 15)];
        unsigned u = f2u(w);
        hv[j] = (short)(u >> 16);
        float hf = u2f(u & 0xFFFF0000u);
        float l = w - hf;
        lv[j] = (short)(f2u(l) >> 16);
    }
    Wh[idx] = hv;
    Wl[idx] = lv;
}

// coalesced csr_cv fill: scattered READS (L2/L3-resident), coalesced writes.
__global__ void gathercv_kernel(const int* __restrict__ perm, const int* __restrict__ colv,
                                const float* __restrict__ ev, int2* __restrict__ csr_cv,
                                int E) {
    int s = blockIdx.x * 256 + threadIdx.x;
    if (s < E) {
        int e = perm[s];
        csr_cv[s] = make_int2(colv[e], __float_as_int(ev[e]));
    }
}

// ---------------- MFMA GEMM body (B staged in LDS) ----------------
// flags: bit0 = add bias, bit1 = alpha epilogue, bit2 = store C as bf16.

__device__ __forceinline__ void
gemm_body(int bid, const float* __restrict__ A, const short8* __restrict__ Bh,
          const short8* __restrict__ Bl, const float* __restrict__ bias,
          const float* __restrict__ avec, float* __restrict__ Cf,
          unsigned short* __restrict__ Cbf,
          float* __restrict__ asrc, float* __restrict__ adst, int n, int flags) {
    // Stage full B fragment table (Wh 32KB + Wl 32KB) in LDS once per block;
    // kills the 1MB/block L2 re-read (B-reads become ds_read_b128).
    __shared__ short8 lb[4096];
    int t = threadIdx.x;
#pragma unroll
    for (int i = 0; i < 8; ++i) lb[i * 256 + t] = Bh[i * 256 + t];
#pragma unroll
    for (int i = 0; i < 8; ++i) lb[2048 + i * 256 + t] = Bl[i * 256 + t];

    int wave = threadIdx.x >> 6;
    int lane = threadIdx.x & 63;
    int q = lane >> 4;
    int col = lane & 15;
    int n0w = bid * 64 + wave * 16;

    int arow = min(n0w + col, n - 1);
    const float* Arow = A + (size_t)arow * 128;
    int kb = q * 8;
    short8 Ah[4], Al[4];
#pragma unroll
    for (int kt = 0; kt < 4; ++kt) {
        float4 f0 = *(const float4*)(Arow + kt * 32 + kb);
        float4 f1 = *(const float4*)(Arow + kt * 32 + kb + 4);
        float fv[8] = {f0.x, f0.y, f0.z, f0.w, f1.x, f1.y, f1.z, f1.w};
#pragma unroll
        for (int j = 0; j < 8; ++j) {
            unsigned u = f2u(fv[j]);
            Ah[kt][j] = (short)(u >> 16);
            float hf = u2f(u & 0xFFFF0000u);
            float l = fv[j] - hf;
            Al[kt][j] = (short)(f2u(l) >> 16);
        }
    }
    __syncthreads();

    int nbase = n0w + q * 4;
#pragma unroll
    for (int ct = 0; ct < 8; ++ct) {
        short8 bh[4], bl[4];
#pragma unroll
        for (int kt = 0; kt < 4; ++kt) {
            bh[kt] = lb[(ct * 4 + kt) * 64 + lane];
            bl[kt] = lb[2048 + (ct * 4 + kt) * 64 + lane];
        }
        float bv = (flags & 1) ? bias[ct * 16 + col] : 0.f;
        floatx4 acc = {bv, bv, bv, bv};
#pragma unroll
        for (int kt = 0; kt < 4; ++kt) {
            acc = __builtin_amdgcn_mfma_f32_16x16x32_bf16(Ah[kt], bh[kt], acc, 0, 0, 0);
            acc = __builtin_amdgcn_mfma_f32_16x16x32_bf16(Al[kt], bh[kt], acc, 0, 0, 0);
            acc = __builtin_amdgcn_mfma_f32_16x16x32_bf16(Ah[kt], bl[kt], acc, 0, 0, 0);
        }
#pragma unroll
        for (int reg = 0; reg < 4; ++reg) {
            int node = nbase + reg;
            if (node < n) {
                if (flags & 4) Cbf[(size_t)node * 128 + ct * 16 + col] = f2bf_rne(acc[reg]);
                else           Cf[(size_t)node * 128 + ct * 16 + col] = acc[reg];
            }
        }
        if (flags & 2) {
            float a_s = avec[ct * 32 + col];
            float a_d = avec[ct * 32 + 16 + col];
#pragma unroll
            for (int reg = 0; reg < 4; ++reg) {
                float ps = acc[reg] * a_s;
                float pd = acc[reg] * a_d;
#pragma unroll
                for (int off = 8; off; off >>= 1) {
                    ps += __shfl_down(ps, off, 16);
                    pd += __shfl_down(pd, off, 16);
                }
                int node = nbase + reg;
                if (col == 0 && node < n) {
                    asrc[node * 8 + ct] = ps;
                    adst[node * 8 + ct] = pd;
                }
            }
        }
    }
}

// standalone GEMM (layer 1)
__global__ __launch_bounds__(256) void
gemm_mfma(const float* __restrict__ A, const short8* __restrict__ Bh,
          const short8* __restrict__ Bl, const float* __restrict__ avec,
          unsigned short* __restrict__ Cbf,
          float* __restrict__ asrc, float* __restrict__ adst, int n) {
    gemm_body(blockIdx.x, A, Bh, Bl, nullptr, avec, nullptr, Cbf, asrc, adst, n, 2 | 4);
}

// fusion A: blocks [0,GBn): encoder GEMM (flags=1). blocks [GBn,GBn+NCH):
// MONOTONIC scan — block cb derives its base by summing chunkdeg[0..cb), then
// local-scans its 256 degrees. rowptr identical to a global exclusive scan.
__global__ __launch_bounds__(256) void
enc_scan_kernel(const float* __restrict__ x, const short8* __restrict__ Wh,
                const short8* __restrict__ Wl, const float* __restrict__ encb,
                float* __restrict__ xc, int n, int GBn,
                const int* __restrict__ deg, const int* __restrict__ chunkdeg,
                int* __restrict__ rowptr) {
    if ((int)blockIdx.x < GBn) {
        gemm_body(blockIdx.x, x, Wh, Wl, encb, nullptr, xc, nullptr, nullptr, nullptr, n, 1);
        return;
    }
    __shared__ int sd[256];
    __shared__ int sbase;
    int t = threadIdx.x;
    int cb = blockIdx.x - GBn;
    int acc = 0;
    for (int k = t; k < cb; k += 256) acc += chunkdeg[k];
    sd[t] = acc;
    __syncthreads();
    for (int off = 128; off; off >>= 1) {
        if (t < off) sd[t] += sd[t + off];
        __syncthreads();
    }
    if (t == 0) sbase = sd[0];
    __syncthreads();
    int idx = cb * 256 + t;
    int v = (idx < n) ? deg[idx] : 0;
    sd[t] = v;
    __syncthreads();
    for (int off = 1; off < 256; off <<= 1) {
        int add = (t >= off) ? sd[t - off] : 0;
        __syncthreads();
        sd[t] += add;
        __syncthreads();
    }
    if (idx < n) rowptr[idx] = sbase + sd[t] - v;
    if (idx == n - 1) rowptr[n] = sbase + sd[t];
}

// fusion B: blocks [0,GBn): layer-0 GEMM (flags=2|4). blocks [GBn,GBn+EB):
// scatterperm — slot = rowptr[r] + rank[e]; only scattered write is 4B perm.
__global__ __launch_bounds__(256) void
sperm_gemm_kernel(const float* __restrict__ xc, const short8* __restrict__ Wh1,
                  const short8* __restrict__ Wl1, const float* __restrict__ avec,
                  unsigned short* __restrict__ hbf, float* __restrict__ asrc,
                  float* __restrict__ adst, int n, int GBn,
                  const int* __restrict__ row, const int* __restrict__ rank,
                  const int* __restrict__ rowptr, int* __restrict__ perm, int E) {
    if ((int)blockIdx.x < GBn) {
        gemm_body(blockIdx.x, xc, Wh1, Wl1, nullptr, avec, nullptr, hbf, asrc, adst, n, 2 | 4);
        return;
    }
    int e = (blockIdx.x - GBn) * 256 + threadIdx.x;
    if (e < E) perm[rowptr[row[e]] + rank[e]] = e;
}

// ---------------- aggregate: one wave per node, no LDS, no barriers (R7) ----------------
// Wave = 64 lanes = 4 edge-parity groups (grp = lane>>4) x 16 feature-lanes
// (l4 = lane&15). Lane owns features 8*l4 .. 8*l4+7 (head l4>>1).
// Group g processes edges j = s+g, s+g+4, ...; unroll 4 => 16 h-rows in
// flight per wave. Accumulators are float2 pairs (v_pk_fma_f32 path).

__global__ __launch_bounds__(256) void
aggregate_kernel(const int* __restrict__ rowptr, const int2* __restrict__ cv,
                 const unsigned short* __restrict__ hbf,
                 const float* __restrict__ asrc, const float* __restrict__ adst,
                 const float* __restrict__ resid, float* __restrict__ out,
                 int mode, int n) {
    int wid = (blockIdx.x * 256 + threadIdx.x) >> 6;   // wave id = node
    if (wid >= n) return;                              // wave-uniform
    int lane = threadIdx.x & 63;
    int grp = lane >> 4;        // edge parity group 0..3
    int l4 = lane & 15;         // feature lane: features 8*l4 .. 8*l4+7
    int h = l4 >> 1;            // head of this lane's features

    int s = rowptr[wid];
    int e = rowptr[wid + 1];
    float as_w = asrc[wid * 8 + h];

    floatx2 acc0 = {0.f, 0.f}, acc1 = {0.f, 0.f};
    floatx2 acc2 = {0.f, 0.f}, acc3 = {0.f, 0.f};
    float ws = 0.f;

#pragma unroll 4
    for (int j = s + grp; j < e; j += 4) {
        int2 cvj = cv[j];
        int c = cvj.x;
        float v = __int_as_float(cvj.y);
        float lg = v * (as_w + adst[c * 8 + h]);
        float lr = fmaxf(lg, 0.2f * lg);     // leaky_relu(0.2)
        float w = __expf(lr);
        uint4 hv = *(const uint4*)(hbf + (size_t)c * 128 + l4 * 8);
        floatx2 w2 = {w, w};
        floatx2 p0 = {u2f(hv.x << 16), u2f(hv.x & 0xFFFF0000u)};
        floatx2 p1 = {u2f(hv.y << 16), u2f(hv.y & 0xFFFF0000u)};
        floatx2 p2 = {u2f(hv.z << 16), u2f(hv.z & 0xFFFF0000u)};
        floatx2 p3 = {u2f(hv.w << 16), u2f(hv.w & 0xFFFF0000u)};
        acc0 += w2 * p0;
        acc1 += w2 * p1;
        acc2 += w2 * p2;
        acc3 += w2 * p3;
        ws += w;
    }

    float a0 = acc0.x, a1 = acc0.y, a2 = acc1.x, a3 = acc1.y;
    float a4 = acc2.x, a5 = acc2.y, a6 = acc3.x, a7 = acc3.y;

#define RED4(x) x += __shfl_xor(x, 16); x += __shfl_xor(x, 32);
    RED4(a0) RED4(a1) RED4(a2) RED4(a3)
    RED4(a4) RED4(a5) RED4(a6) RED4(a7)
    RED4(ws)
#undef RED4

    if (grp == 0) {
        float inv = 1.0f / ws;   // self-loop guarantees ws > 0
        float o[8] = {a0 * inv, a1 * inv, a2 * inv, a3 * inv,
                      a4 * inv, a5 * inv, a6 * inv, a7 * inv};
        size_t base = (size_t)wid * 128 + l4 * 8;
        if (mode == 0) {
#pragma unroll
            for (int k = 0; k < 8; ++k) o[k] = o[k] > 0.f ? o[k] : expm1f(o[k]);
        } else {
            float4 r0 = *(const float4*)(resid + base);
            float4 r1 = *(const float4*)(resid + base + 4);
            o[0] += r0.x; o[1] += r0.y; o[2] += r0.z; o[3] += r0.w;
            o[4] += r1.x; o[5] += r1.y; o[6] += r1.z; o[7] += r1.w;
        }
        float4 w0 = {o[0], o[1], o[2], o[3]};
        float4 w1 = {o[4], o[5], o[6], o[7]};
        *(float4*)(out + base) = w0;
        *(float4*)(out + base + 4) = w1;
    }
}

// ---------------- launch ----------------

extern "C" void kernel_launch(void* const* d_in, const int* in_sizes, int n_in,
                              void* d_out, int out_size, void* d_ws, size_t ws_size,
                              hipStream_t stream) {
    const int N = in_sizes[0] / 128;
    const int E = in_sizes[2];

    const float* x      = (const float*)d_in[0];
    const int*   eidx   = (const int*)d_in[1];
    const float* ev     = (const float*)d_in[2];
    const float* encW   = (const float*)d_in[3];
    const float* encb   = (const float*)d_in[4];
    const float* Wstack = (const float*)d_in[5];
    const float* astack = (const float*)d_in[6];
    float* out = (float*)d_out;

    const int* row = eidx;
    const int* colv = eidx + E;

    const int NCH = (N + 255) / 256;   // 256-node chunks for monotonic scan

    char* p = (char*)d_ws;
    float* xc   = (float*)p; p += (size_t)N * 128 * 4;
    float* xcB  = (float*)p; p += (size_t)N * 128 * 4;
    unsigned short* hbf = (unsigned short*)p; p += (size_t)N * 128 * 2;
    float* asrc = (float*)p; p += (size_t)N * 8 * 4;
    float* adst = (float*)p; p += (size_t)N * 8 * 4;
    short8* Wh  = (short8*)p; p += 3 * 2048 * 16;
    short8* Wl  = (short8*)p; p += 3 * 2048 * 16;
    int2* csr_cv = (int2*)p; p += (size_t)E * 8;     // 8B-aligned
    int* rowptr = (int*)p;   p += (size_t)(N + 1) * 4;
    int* deg    = (int*)p;   p += (size_t)N * 4;
    int* chunkdeg = (int*)p; p += (size_t)NCH * 4;   // adjacent to deg: one memset

    // rank/perm alias the xcB buffer: rank dead after sperm_gemm, perm dead
    // after gathercv; xcB first written by agg0 (after gathercv). Stream-ordered.
    // (NOT xc — encoder writes xc concurrently with scan in enc_scan_kernel.)
    int* rank = (int*)xcB;
    int* perm = rank + E;

    const int GB = (N + 63) / 64;
    const int AGG = (N + 3) / 4;   // 4 nodes (waves) per 256-thread block
    const int EB = (E + 255) / 256;

    // --- CSR build + weight pack (fused) ---
    hipMemsetAsync(deg, 0, (size_t)(N + NCH) * 4, stream);   // deg + chunkdeg
    histpack_kernel<<<EB + 24, 256, 0, stream>>>(row, deg, chunkdeg, rank, E, EB, NCH,
                                                 encW, Wstack, Wh, Wl);

    // --- encoder GEMM || monotonic degree scan ---
    enc_scan_kernel<<<GB + NCH, 256, 0, stream>>>(x, Wh, Wl, encb, xc, N, GB,
                                                  deg, chunkdeg, rowptr);

    // --- layer-0 GEMM || scatterperm ---
    sperm_gemm_kernel<<<GB + EB, 256, 0, stream>>>(xc, Wh + 2048, Wl + 2048, astack,
                                                   hbf, asrc, adst, N, GB,
                                                   row, rank, rowptr, perm, E);

    // --- csr_cv fill (coalesced) ---
    gathercv_kernel<<<EB, 256, 0, stream>>>(perm, colv, ev, csr_cv, E);

    // --- layer 0 aggregate ---
    aggregate_kernel<<<AGG, 256, 0, stream>>>(rowptr, csr_cv, hbf, asrc, adst,
                                              nullptr, xcB, 0, N);

    // --- layer 1: h1 (bf16) + alpha1 ---
    gemm_mfma<<<GB, 256, 0, stream>>>(xcB, Wh + 4096, Wl + 4096, astack + 256,
                                      hbf, asrc, adst, N);
    aggregate_kernel<<<AGG, 256, 0, stream>>>(rowptr, csr_cv, hbf, asrc, adst,
                                              xcB, out, 1, N);
}

// Round 8
// 322.879 us; speedup vs baseline: 1.1302x; 1.1302x over previous
//
#include <hip/hip_runtime.h>
#include <hip/hip_bf16.h>

// GAT: N=50000, E=850000, HID=128, HEADS=8, DH=16, LAYERS=2.
// R11: histpack reverted to R9 (R10's chunk-histogram serialized on 196 hot
//      atomic addresses: 99us). Monotonic rowptr kept via direct strided
//      deg-prefix sum per scan block (L2-resident, no atomics). GEMM LDS
//      B-staging only in standalone layer-1 GEMM (fused partners keep
//      full occupancy).

typedef __attribute__((ext_vector_type(8))) short short8;   // 8 bf16 = 4 VGPRs
typedef __attribute__((ext_vector_type(4))) float floatx4;
typedef __attribute__((ext_vector_type(2))) float floatx2;

__device__ __forceinline__ unsigned f2u(float f) { return __float_as_uint(f); }
__device__ __forceinline__ float u2f(unsigned u) { return __uint_as_float(u); }
__device__ __forceinline__ unsigned short f2bf_rne(float x) {
    unsigned u = f2u(x);
    unsigned r = (u + 0x7FFF + ((u >> 16) & 1)) >> 16;
    return (unsigned short)r;
}

// ---------------- CSR build ----------------

// blocks [0, EB): histogram + rank capture. blocks [EB, EB+24): weight pack.
__global__ void histpack_kernel(const int* __restrict__ row, int* __restrict__ deg,
                                int* __restrict__ rank, int E, int EB,
                                const float* __restrict__ encW,
                                const float* __restrict__ Wstack,
                                short8* __restrict__ Wh, short8* __restrict__ Wl) {
    int b = blockIdx.x;
    if (b < EB) {
        int e = b * 256 + threadIdx.x;
        if (e < E) rank[e] = atomicAdd(&deg[row[e]], 1);
        return;
    }
    int idx = (b - EB) * 256 + threadIdx.x;
    if (idx >= 3 * 2048) return;
    int mat = idx >> 11;
    int r = idx & 2047;
    int lane = r & 63;
    int tile = r >> 6;            // ct*4 + kt
    int ct = tile >> 2, kt = tile & 3;
    int ncol = ct * 16 + (lane & 15);
    int k0 = kt * 32 + ((lane >> 4) * 8);
    short8 hv, lv;
#pragma unroll
    for (int j = 0; j < 8; ++j) {
        int k = k0 + j;
        float w = (mat == 0)
            ? encW[k * 128 + ncol]
            : Wstack[(mat - 1) * 16384 + (ncol >> 4) * 2048 + k * 16 + (ncol & 15)];
        unsigned u = f2u(w);
        hv[j] = (short)(u >> 16);
        float hf = u2f(u & 0xFFFF0000u);
        float l = w - hf;
        lv[j] = (short)(f2u(l) >> 16);
    }
    Wh[idx] = hv;
    Wl[idx] = lv;
}

// coalesced csr_cv fill: scattered READS (L2/L3-resident), coalesced writes.
__global__ void gathercv_kernel(const int* __restrict__ perm, const int* __restrict__ colv,
                                const float* __restrict__ ev, int2* __restrict__ csr_cv,
                                int E) {
    int s = blockIdx.x * 256 + threadIdx.x;
    if (s < E) {
        int e = perm[s];
        csr_cv[s] = make_int2(colv[e], __float_as_int(ev[e]));
    }
}

// ---------------- MFMA GEMM body ----------------
// flags: bit0 = add bias, bit1 = alpha epilogue, bit2 = store C as bf16.
// STAGE: stage Wh+Wl (64KB) in LDS (only for standalone GEMM — costs 2 blk/CU).

template <bool STAGE>
__device__ __forceinline__ void
gemm_body(int bid, const float* __restrict__ A, const short8* __restrict__ Bh,
          const short8* __restrict__ Bl, const float* __restrict__ bias,
          const float* __restrict__ avec, float* __restrict__ Cf,
          unsigned short* __restrict__ Cbf,
          float* __restrict__ asrc, float* __restrict__ adst, int n, int flags) {
    int t = threadIdx.x;
    int wave = t >> 6;
    int lane = t & 63;
    int q = lane >> 4;
    int col = lane & 15;
    int n0w = bid * 64 + wave * 16;

    int arow = min(n0w + col, n - 1);
    const float* Arow = A + (size_t)arow * 128;
    int kb = q * 8;
    short8 Ah[4], Al[4];
#pragma unroll
    for (int kt = 0; kt < 4; ++kt) {
        float4 f0 = *(const float4*)(Arow + kt * 32 + kb);
        float4 f1 = *(const float4*)(Arow + kt * 32 + kb + 4);
        float fv[8] = {f0.x, f0.y, f0.z, f0.w, f1.x, f1.y, f1.z, f1.w};
#pragma unroll
        for (int j = 0; j < 8; ++j) {
            unsigned u = f2u(fv[j]);
            Ah[kt][j] = (short)(u >> 16);
            float hf = u2f(u & 0xFFFF0000u);
            float l = fv[j] - hf;
            Al[kt][j] = (short)(f2u(l) >> 16);
        }
    }

    int nbase = n0w + q * 4;
#pragma unroll
    for (int ct = 0; ct < 8; ++ct) {
        short8 bh[4], bl[4];
        if constexpr (STAGE) {
            __shared__ short8 lb[4096];
            if (ct == 0) {
#pragma unroll
                for (int i = 0; i < 8; ++i) lb[i * 256 + t] = Bh[i * 256 + t];
#pragma unroll
                for (int i = 0; i < 8; ++i) lb[2048 + i * 256 + t] = Bl[i * 256 + t];
                __syncthreads();
            }
#pragma unroll
            for (int kt = 0; kt < 4; ++kt) {
                bh[kt] = lb[(ct * 4 + kt) * 64 + lane];
                bl[kt] = lb[2048 + (ct * 4 + kt) * 64 + lane];
            }
        } else {
#pragma unroll
            for (int kt = 0; kt < 4; ++kt) {
                bh[kt] = Bh[(ct * 4 + kt) * 64 + lane];
                bl[kt] = Bl[(ct * 4 + kt) * 64 + lane];
            }
        }
        float bv = (flags & 1) ? bias[ct * 16 + col] : 0.f;
        floatx4 acc = {bv, bv, bv, bv};
#pragma unroll
        for (int kt = 0; kt < 4; ++kt) {
            acc = __builtin_amdgcn_mfma_f32_16x16x32_bf16(Ah[kt], bh[kt], acc, 0, 0, 0);
            acc = __builtin_amdgcn_mfma_f32_16x16x32_bf16(Al[kt], bh[kt], acc, 0, 0, 0);
            acc = __builtin_amdgcn_mfma_f32_16x16x32_bf16(Ah[kt], bl[kt], acc, 0, 0, 0);
        }
#pragma unroll
        for (int reg = 0; reg < 4; ++reg) {
            int node = nbase + reg;
            if (node < n) {
                if (flags & 4) Cbf[(size_t)node * 128 + ct * 16 + col] = f2bf_rne(acc[reg]);
                else           Cf[(size_t)node * 128 + ct * 16 + col] = acc[reg];
            }
        }
        if (flags & 2) {
            float a_s = avec[ct * 32 + col];
            float a_d = avec[ct * 32 + 16 + col];
#pragma unroll
            for (int reg = 0; reg < 4; ++reg) {
                float ps = acc[reg] * a_s;
                float pd = acc[reg] * a_d;
#pragma unroll
                for (int off = 8; off; off >>= 1) {
                    ps += __shfl_down(ps, off, 16);
                    pd += __shfl_down(pd, off, 16);
                }
                int node = nbase + reg;
                if (col == 0 && node < n) {
                    asrc[node * 8 + ct] = ps;
                    adst[node * 8 + ct] = pd;
                }
            }
        }
    }
}

// standalone GEMM (layer 1) — LDS-staged B
__global__ __launch_bounds__(256) void
gemm_mfma(const float* __restrict__ A, const short8* __restrict__ Bh,
          const short8* __restrict__ Bl, const float* __restrict__ avec,
          unsigned short* __restrict__ Cbf,
          float* __restrict__ asrc, float* __restrict__ adst, int n) {
    gemm_body<true>(blockIdx.x, A, Bh, Bl, nullptr, avec, nullptr, Cbf, asrc, adst, n, 2 | 4);
}

// fusion A: blocks [0,GBn): encoder GEMM (flags=1). blocks [GBn,GBn+NCH):
// MONOTONIC scan — block cb sums deg[0..cb*256) directly (deg is L2-resident,
// 200KB; no atomics, no histogram), then local-scans its 256 degrees.
// rowptr identical to a global exclusive scan.
__global__ __launch_bounds__(256) void
enc_scan_kernel(const float* __restrict__ x, const short8* __restrict__ Wh,
                const short8* __restrict__ Wl, const float* __restrict__ encb,
                float* __restrict__ xc, int n, int GBn,
                const int* __restrict__ deg, int* __restrict__ rowptr) {
    if ((int)blockIdx.x < GBn) {
        gemm_body<false>(blockIdx.x, x, Wh, Wl, encb, nullptr, xc, nullptr,
                         nullptr, nullptr, n, 1);
        return;
    }
    __shared__ int sd[256];
    __shared__ int sbase;
    int t = threadIdx.x;
    int cb = blockIdx.x - GBn;
    int lim = cb * 256;
    int acc = 0;
    for (int k = t; k < lim; k += 256) acc += deg[k];
    sd[t] = acc;
    __syncthreads();
    for (int off = 128; off; off >>= 1) {
        if (t < off) sd[t] += sd[t + off];
        __syncthreads();
    }
    if (t == 0) sbase = sd[0];
    __syncthreads();
    int idx = lim + t;
    int v = (idx < n) ? deg[idx] : 0;
    sd[t] = v;
    __syncthreads();
    for (int off = 1; off < 256; off <<= 1) {
        int add = (t >= off) ? sd[t - off] : 0;
        __syncthreads();
        sd[t] += add;
        __syncthreads();
    }
    if (idx < n) rowptr[idx] = sbase + sd[t] - v;
    if (idx == n - 1) rowptr[n] = sbase + sd[t];
}

// fusion B: blocks [0,GBn): layer-0 GEMM (flags=2|4). blocks [GBn,GBn+EB):
// scatterperm — slot = rowptr[r] + rank[e]; only scattered write is 4B perm.
__global__ __launch_bounds__(256) void
sperm_gemm_kernel(const float* __restrict__ xc, const short8* __restrict__ Wh1,
                  const short8* __restrict__ Wl1, const float* __restrict__ avec,
                  unsigned short* __restrict__ hbf, float* __restrict__ asrc,
                  float* __restrict__ adst, int n, int GBn,
                  const int* __restrict__ row, const int* __restrict__ rank,
                  const int* __restrict__ rowptr, int* __restrict__ perm, int E) {
    if ((int)blockIdx.x < GBn) {
        gemm_body<false>(blockIdx.x, xc, Wh1, Wl1, nullptr, avec, nullptr, hbf,
                         asrc, adst, n, 2 | 4);
        return;
    }
    int e = (blockIdx.x - GBn) * 256 + threadIdx.x;
    if (e < E) perm[rowptr[row[e]] + rank[e]] = e;
}

// ---------------- aggregate: one wave per node, no LDS, no barriers (R7) ----------------
// Wave = 64 lanes = 4 edge-parity groups (grp = lane>>4) x 16 feature-lanes
// (l4 = lane&15). Lane owns features 8*l4 .. 8*l4+7 (head l4>>1).
// Group g processes edges j = s+g, s+g+4, ...; unroll 4 => 16 h-rows in
// flight per wave. Accumulators are float2 pairs (v_pk_fma_f32 path).

__global__ __launch_bounds__(256) void
aggregate_kernel(const int* __restrict__ rowptr, const int2* __restrict__ cv,
                 const unsigned short* __restrict__ hbf,
                 const float* __restrict__ asrc, const float* __restrict__ adst,
                 const float* __restrict__ resid, float* __restrict__ out,
                 int mode, int n) {
    int wid = (blockIdx.x * 256 + threadIdx.x) >> 6;   // wave id = node
    if (wid >= n) return;                              // wave-uniform
    int lane = threadIdx.x & 63;
    int grp = lane >> 4;        // edge parity group 0..3
    int l4 = lane & 15;         // feature lane: features 8*l4 .. 8*l4+7
    int h = l4 >> 1;            // head of this lane's features

    int s = rowptr[wid];
    int e = rowptr[wid + 1];
    float as_w = asrc[wid * 8 + h];

    floatx2 acc0 = {0.f, 0.f}, acc1 = {0.f, 0.f};
    floatx2 acc2 = {0.f, 0.f}, acc3 = {0.f, 0.f};
    float ws = 0.f;

#pragma unroll 4
    for (int j = s + grp; j < e; j += 4) {
        int2 cvj = cv[j];
        int c = cvj.x;
        float v = __int_as_float(cvj.y);
        float lg = v * (as_w + adst[c * 8 + h]);
        float lr = fmaxf(lg, 0.2f * lg);     // leaky_relu(0.2)
        float w = __expf(lr);
        uint4 hv = *(const uint4*)(hbf + (size_t)c * 128 + l4 * 8);
        floatx2 w2 = {w, w};
        floatx2 p0 = {u2f(hv.x << 16), u2f(hv.x & 0xFFFF0000u)};
        floatx2 p1 = {u2f(hv.y << 16), u2f(hv.y & 0xFFFF0000u)};
        floatx2 p2 = {u2f(hv.z << 16), u2f(hv.z & 0xFFFF0000u)};
        floatx2 p3 = {u2f(hv.w << 16), u2f(hv.w & 0xFFFF0000u)};
        acc0 += w2 * p0;
        acc1 += w2 * p1;
        acc2 += w2 * p2;
        acc3 += w2 * p3;
        ws += w;
    }

    float a0 = acc0.x, a1 = acc0.y, a2 = acc1.x, a3 = acc1.y;
    float a4 = acc2.x, a5 = acc2.y, a6 = acc3.x, a7 = acc3.y;

#define RED4(x) x += __shfl_xor(x, 16); x += __shfl_xor(x, 32);
    RED4(a0) RED4(a1) RED4(a2) RED4(a3)
    RED4(a4) RED4(a5) RED4(a6) RED4(a7)
    RED4(ws)
#undef RED4

    if (grp == 0) {
        float inv = 1.0f / ws;   // self-loop guarantees ws > 0
        float o[8] = {a0 * inv, a1 * inv, a2 * inv, a3 * inv,
                      a4 * inv, a5 * inv, a6 * inv, a7 * inv};
        size_t base = (size_t)wid * 128 + l4 * 8;
        if (mode == 0) {
#pragma unroll
            for (int k = 0; k < 8; ++k) o[k] = o[k] > 0.f ? o[k] : expm1f(o[k]);
        } else {
            float4 r0 = *(const float4*)(resid + base);
            float4 r1 = *(const float4*)(resid + base + 4);
            o[0] += r0.x; o[1] += r0.y; o[2] += r0.z; o[3] += r0.w;
            o[4] += r1.x; o[5] += r1.y; o[6] += r1.z; o[7] += r1.w;
        }
        float4 w0 = {o[0], o[1], o[2], o[3]};
        float4 w1 = {o[4], o[5], o[6], o[7]};
        *(float4*)(out + base) = w0;
        *(float4*)(out + base + 4) = w1;
    }
}

// ---------------- launch ----------------

extern "C" void kernel_launch(void* const* d_in, const int* in_sizes, int n_in,
                              void* d_out, int out_size, void* d_ws, size_t ws_size,
                              hipStream_t stream) {
    const int N = in_sizes[0] / 128;
    const int E = in_sizes[2];

    const float* x      = (const float*)d_in[0];
    const int*   eidx   = (const int*)d_in[1];
    const float* ev     = (const float*)d_in[2];
    const float* encW   = (const float*)d_in[3];
    const float* encb   = (const float*)d_in[4];
    const float* Wstack = (const float*)d_in[5];
    const float* astack = (const float*)d_in[6];
    float* out = (float*)d_out;

    const int* row = eidx;
    const int* colv = eidx + E;

    const int NCH = (N + 255) / 256;   // 256-node chunks for monotonic scan

    char* p = (char*)d_ws;
    float* xc   = (float*)p; p += (size_t)N * 128 * 4;
    float* xcB  = (float*)p; p += (size_t)N * 128 * 4;
    unsigned short* hbf = (unsigned short*)p; p += (size_t)N * 128 * 2;
    float* asrc = (float*)p; p += (size_t)N * 8 * 4;
    float* adst = (float*)p; p += (size_t)N * 8 * 4;
    short8* Wh  = (short8*)p; p += 3 * 2048 * 16;
    short8* Wl  = (short8*)p; p += 3 * 2048 * 16;
    int2* csr_cv = (int2*)p; p += (size_t)E * 8;     // 8B-aligned
    int* rowptr = (int*)p;   p += (size_t)(N + 1) * 4;
    int* deg    = (int*)p;   p += (size_t)N * 4;

    // rank/perm alias the xcB buffer: rank dead after sperm_gemm, perm dead
    // after gathercv; xcB first written by agg0 (after gathercv). Stream-ordered.
    // (NOT xc — encoder writes xc concurrently with scan in enc_scan_kernel.)
    int* rank = (int*)xcB;
    int* perm = rank + E;

    const int GB = (N + 63) / 64;
    const int AGG = (N + 3) / 4;   // 4 nodes (waves) per 256-thread block
    const int EB = (E + 255) / 256;

    // --- CSR build + weight pack (fused) ---
    hipMemsetAsync(deg, 0, (size_t)N * 4, stream);
    histpack_kernel<<<EB + 24, 256, 0, stream>>>(row, deg, rank, E, EB,
                                                 encW, Wstack, Wh, Wl);

    // --- encoder GEMM || monotonic degree scan ---
    enc_scan_kernel<<<GB + NCH, 256, 0, stream>>>(x, Wh, Wl, encb, xc, N, GB,
                                                  deg, rowptr);

    // --- layer-0 GEMM || scatterperm ---
    sperm_gemm_kernel<<<GB + EB, 256, 0, stream>>>(xc, Wh + 2048, Wl + 2048, astack,
                                                   hbf, asrc, adst, N, GB,
                                                   row, rank, rowptr, perm, E);

    // --- csr_cv fill (coalesced) ---
    gathercv_kernel<<<EB, 256, 0, stream>>>(perm, colv, ev, csr_cv, E);

    // --- layer 0 aggregate ---
    aggregate_kernel<<<AGG, 256, 0, stream>>>(rowptr, csr_cv, hbf, asrc, adst,
                                              nullptr, xcB, 0, N);

    // --- layer 1: h1 (bf16) + alpha1 ---
    gemm_mfma<<<GB, 256, 0, stream>>>(xcB, Wh + 4096, Wl + 4096, astack + 256,
                                      hbf, asrc, adst, N);
    aggregate_kernel<<<AGG, 256, 0, stream>>>(rowptr, csr_cv, hbf, asrc, adst,
                                              xcB, out, 1, N);
}

// Round 9
// 297.075 us; speedup vs baseline: 1.2284x; 1.0869x over previous
//
#include <hip/hip_runtime.h>
#include <hip/hip_bf16.h>

// GAT: N=50000, E=850000, HID=128, HEADS=8, DH=16, LAYERS=2.
// R12: keep monotonic rowptr (aggregate 50.2->46.2 confirmed) but fix its cost:
//      scan-base now int4-vectorized strided sum w/ 4 accumulators (49 iters
//      max vs 195 scalar latency-bound iters). LDS B-staging reverted (R9
//      plain gemm body everywhere) to keep attribution clean.

typedef __attribute__((ext_vector_type(8))) short short8;   // 8 bf16 = 4 VGPRs
typedef __attribute__((ext_vector_type(4))) float floatx4;
typedef __attribute__((ext_vector_type(2))) float floatx2;

__device__ __forceinline__ unsigned f2u(float f) { return __float_as_uint(f); }
__device__ __forceinline__ float u2f(unsigned u) { return __uint_as_float(u); }
__device__ __forceinline__ unsigned short f2bf_rne(float x) {
    unsigned u = f2u(x);
    unsigned r = (u + 0x7FFF + ((u >> 16) & 1)) >> 16;
    return (unsigned short)r;
}

// ---------------- CSR build ----------------

// blocks [0, EB): histogram + rank capture. blocks [EB, EB+24): weight pack.
__global__ void histpack_kernel(const int* __restrict__ row, int* __restrict__ deg,
                                int* __restrict__ rank, int E, int EB,
                                const float* __restrict__ encW,
                                const float* __restrict__ Wstack,
                                short8* __restrict__ Wh, short8* __restrict__ Wl) {
    int b = blockIdx.x;
    if (b < EB) {
        int e = b * 256 + threadIdx.x;
        if (e < E) rank[e] = atomicAdd(&deg[row[e]], 1);
        return;
    }
    int idx = (b - EB) * 256 + threadIdx.x;
    if (idx >= 3 * 2048) return;
    int mat = idx >> 11;
    int r = idx & 2047;
    int lane = r & 63;
    int tile = r >> 6;            // ct*4 + kt
    int ct = tile >> 2, kt = tile & 3;
    int ncol = ct * 16 + (lane & 15);
    int k0 = kt * 32 + ((lane >> 4) * 8);
    short8 hv, lv;
#pragma unroll
    for (int j = 0; j < 8; ++j) {
        int k = k0 + j;
        float w = (mat == 0)
            ? encW[k * 128 + ncol]
            : Wstack[(mat - 1) * 16384 + (ncol >> 4) * 2048 + k * 16 + (ncol & 15)];
        unsigned u = f2u(w);
        hv[j] = (short)(u >> 16);
        float hf = u2f(u & 0xFFFF0000u);
        float l = w - hf;
        lv[j] = (short)(f2u(l) >> 16);
    }
    Wh[idx] = hv;
    Wl[idx] = lv;
}

// coalesced csr_cv fill: scattered READS (L2/L3-resident), coalesced writes.
__global__ void gathercv_kernel(const int* __restrict__ perm, const int* __restrict__ colv,
                                const float* __restrict__ ev, int2* __restrict__ csr_cv,
                                int E) {
    int s = blockIdx.x * 256 + threadIdx.x;
    if (s < E) {
        int e = perm[s];
        csr_cv[s] = make_int2(colv[e], __float_as_int(ev[e]));
    }
}

// ---------------- MFMA GEMM body (R9-proven, no LDS) ----------------
// flags: bit0 = add bias, bit1 = alpha epilogue, bit2 = store C as bf16.

__device__ __forceinline__ void
gemm_body(int bid, const float* __restrict__ A, const short8* __restrict__ Bh,
          const short8* __restrict__ Bl, const float* __restrict__ bias,
          const float* __restrict__ avec, float* __restrict__ Cf,
          unsigned short* __restrict__ Cbf,
          float* __restrict__ asrc, float* __restrict__ adst, int n, int flags) {
    int wave = threadIdx.x >> 6;
    int lane = threadIdx.x & 63;
    int q = lane >> 4;
    int col = lane & 15;
    int n0w = bid * 64 + wave * 16;

    int arow = min(n0w + col, n - 1);
    const float* Arow = A + (size_t)arow * 128;
    int kb = q * 8;
    short8 Ah[4], Al[4];
#pragma unroll
    for (int kt = 0; kt < 4; ++kt) {
        float4 f0 = *(const float4*)(Arow + kt * 32 + kb);
        float4 f1 = *(const float4*)(Arow + kt * 32 + kb + 4);
        float fv[8] = {f0.x, f0.y, f0.z, f0.w, f1.x, f1.y, f1.z, f1.w};
#pragma unroll
        for (int j = 0; j < 8; ++j) {
            unsigned u = f2u(fv[j]);
            Ah[kt][j] = (short)(u >> 16);
            float hf = u2f(u & 0xFFFF0000u);
            float l = fv[j] - hf;
            Al[kt][j] = (short)(f2u(l) >> 16);
        }
    }

    int nbase = n0w + q * 4;
#pragma unroll
    for (int ct = 0; ct < 8; ++ct) {
        short8 bh[4], bl[4];
#pragma unroll
        for (int kt = 0; kt < 4; ++kt) {
            bh[kt] = Bh[(ct * 4 + kt) * 64 + lane];
            bl[kt] = Bl[(ct * 4 + kt) * 64 + lane];
        }
        float bv = (flags & 1) ? bias[ct * 16 + col] : 0.f;
        floatx4 acc = {bv, bv, bv, bv};
#pragma unroll
        for (int kt = 0; kt < 4; ++kt) {
            acc = __builtin_amdgcn_mfma_f32_16x16x32_bf16(Ah[kt], bh[kt], acc, 0, 0, 0);
            acc = __builtin_amdgcn_mfma_f32_16x16x32_bf16(Al[kt], bh[kt], acc, 0, 0, 0);
            acc = __builtin_amdgcn_mfma_f32_16x16x32_bf16(Ah[kt], bl[kt], acc, 0, 0, 0);
        }
#pragma unroll
        for (int reg = 0; reg < 4; ++reg) {
            int node = nbase + reg;
            if (node < n) {
                if (flags & 4) Cbf[(size_t)node * 128 + ct * 16 + col] = f2bf_rne(acc[reg]);
                else           Cf[(size_t)node * 128 + ct * 16 + col] = acc[reg];
            }
        }
        if (flags & 2) {
            float a_s = avec[ct * 32 + col];
            float a_d = avec[ct * 32 + 16 + col];
#pragma unroll
            for (int reg = 0; reg < 4; ++reg) {
                float ps = acc[reg] * a_s;
                float pd = acc[reg] * a_d;
#pragma unroll
                for (int off = 8; off; off >>= 1) {
                    ps += __shfl_down(ps, off, 16);
                    pd += __shfl_down(pd, off, 16);
                }
                int node = nbase + reg;
                if (col == 0 && node < n) {
                    asrc[node * 8 + ct] = ps;
                    adst[node * 8 + ct] = pd;
                }
            }
        }
    }
}

// standalone GEMM (layer 1)
__global__ __launch_bounds__(256) void
gemm_mfma(const float* __restrict__ A, const short8* __restrict__ Bh,
          const short8* __restrict__ Bl, const float* __restrict__ avec,
          unsigned short* __restrict__ Cbf,
          float* __restrict__ asrc, float* __restrict__ adst, int n) {
    gemm_body(blockIdx.x, A, Bh, Bl, nullptr, avec, nullptr, Cbf, asrc, adst, n, 2 | 4);
}

// fusion A: blocks [0,GBn): encoder GEMM (flags=1). blocks [GBn,GBn+NCH):
// MONOTONIC scan — block cb sums deg[0..cb*256) via int4 strided loads with
// 4 independent accumulators (<=49 iters, ILP-4; deg is L2-resident 200KB),
// then local-scans its 256 degrees. rowptr == global exclusive scan.
__global__ __launch_bounds__(256) void
enc_scan_kernel(const float* __restrict__ x, const short8* __restrict__ Wh,
                const short8* __restrict__ Wl, const float* __restrict__ encb,
                float* __restrict__ xc, int n, int GBn,
                const int* __restrict__ deg, int* __restrict__ rowptr) {
    if ((int)blockIdx.x < GBn) {
        gemm_body(blockIdx.x, x, Wh, Wl, encb, nullptr, xc, nullptr,
                  nullptr, nullptr, n, 1);
        return;
    }
    __shared__ int sd[256];
    __shared__ int sbase;
    int t = threadIdx.x;
    int cb = blockIdx.x - GBn;
    int lim = cb * 256;
    const int4* deg4 = (const int4*)deg;   // deg is 16B-aligned (ws layout)
    int lim4 = lim >> 2;
    int b0 = 0, b1 = 0, b2 = 0, b3 = 0;
    for (int k = t; k < lim4; k += 256) {
        int4 d = deg4[k];
        b0 += d.x; b1 += d.y; b2 += d.z; b3 += d.w;
    }
    sd[t] = (b0 + b1) + (b2 + b3);
    __syncthreads();
    for (int off = 128; off; off >>= 1) {
        if (t < off) sd[t] += sd[t + off];
        __syncthreads();
    }
    if (t == 0) sbase = sd[0];
    __syncthreads();
    int idx = lim + t;
    int v = (idx < n) ? deg[idx] : 0;
    sd[t] = v;
    __syncthreads();
    for (int off = 1; off < 256; off <<= 1) {
        int add = (t >= off) ? sd[t - off] : 0;
        __syncthreads();
        sd[t] += add;
        __syncthreads();
    }
    if (idx < n) rowptr[idx] = sbase + sd[t] - v;
    if (idx == n - 1) rowptr[n] = sbase + sd[t];
}

// fusion B: blocks [0,GBn): layer-0 GEMM (flags=2|4). blocks [GBn,GBn+EB):
// scatterperm — slot = rowptr[r] + rank[e]; only scattered write is 4B perm.
__global__ __launch_bounds__(256) void
sperm_gemm_kernel(const float* __restrict__ xc, const short8* __restrict__ Wh1,
                  const short8* __restrict__ Wl1, const float* __restrict__ avec,
                  unsigned short* __restrict__ hbf, float* __restrict__ asrc,
                  float* __restrict__ adst, int n, int GBn,
                  const int* __restrict__ row, const int* __restrict__ rank,
                  const int* __restrict__ rowptr, int* __restrict__ perm, int E) {
    if ((int)blockIdx.x < GBn) {
        gemm_body(blockIdx.x, xc, Wh1, Wl1, nullptr, avec, nullptr, hbf,
                  asrc, adst, n, 2 | 4);
        return;
    }
    int e = (blockIdx.x - GBn) * 256 + threadIdx.x;
    if (e < E) perm[rowptr[row[e]] + rank[e]] = e;
}

// ---------------- aggregate: one wave per node, no LDS, no barriers (R7) ----------------
// Wave = 64 lanes = 4 edge-parity groups (grp = lane>>4) x 16 feature-lanes
// (l4 = lane&15). Lane owns features 8*l4 .. 8*l4+7 (head l4>>1).
// Group g processes edges j = s+g, s+g+4, ...; unroll 4 => 16 h-rows in
// flight per wave. Accumulators are float2 pairs (v_pk_fma_f32 path).

__global__ __launch_bounds__(256) void
aggregate_kernel(const int* __restrict__ rowptr, const int2* __restrict__ cv,
                 const unsigned short* __restrict__ hbf,
                 const float* __restrict__ asrc, const float* __restrict__ adst,
                 const float* __restrict__ resid, float* __restrict__ out,
                 int mode, int n) {
    int wid = (blockIdx.x * 256 + threadIdx.x) >> 6;   // wave id = node
    if (wid >= n) return;                              // wave-uniform
    int lane = threadIdx.x & 63;
    int grp = lane >> 4;        // edge parity group 0..3
    int l4 = lane & 15;         // feature lane: features 8*l4 .. 8*l4+7
    int h = l4 >> 1;            // head of this lane's features

    int s = rowptr[wid];
    int e = rowptr[wid + 1];
    float as_w = asrc[wid * 8 + h];

    floatx2 acc0 = {0.f, 0.f}, acc1 = {0.f, 0.f};
    floatx2 acc2 = {0.f, 0.f}, acc3 = {0.f, 0.f};
    float ws = 0.f;

#pragma unroll 4
    for (int j = s + grp; j < e; j += 4) {
        int2 cvj = cv[j];
        int c = cvj.x;
        float v = __int_as_float(cvj.y);
        float lg = v * (as_w + adst[c * 8 + h]);
        float lr = fmaxf(lg, 0.2f * lg);     // leaky_relu(0.2)
        float w = __expf(lr);
        uint4 hv = *(const uint4*)(hbf + (size_t)c * 128 + l4 * 8);
        floatx2 w2 = {w, w};
        floatx2 p0 = {u2f(hv.x << 16), u2f(hv.x & 0xFFFF0000u)};
        floatx2 p1 = {u2f(hv.y << 16), u2f(hv.y & 0xFFFF0000u)};
        floatx2 p2 = {u2f(hv.z << 16), u2f(hv.z & 0xFFFF0000u)};
        floatx2 p3 = {u2f(hv.w << 16), u2f(hv.w & 0xFFFF0000u)};
        acc0 += w2 * p0;
        acc1 += w2 * p1;
        acc2 += w2 * p2;
        acc3 += w2 * p3;
        ws += w;
    }

    float a0 = acc0.x, a1 = acc0.y, a2 = acc1.x, a3 = acc1.y;
    float a4 = acc2.x, a5 = acc2.y, a6 = acc3.x, a7 = acc3.y;

#define RED4(x) x += __shfl_xor(x, 16); x += __shfl_xor(x, 32);
    RED4(a0) RED4(a1) RED4(a2) RED4(a3)
    RED4(a4) RED4(a5) RED4(a6) RED4(a7)
    RED4(ws)
#undef RED4

    if (grp == 0) {
        float inv = 1.0f / ws;   // self-loop guarantees ws > 0
        float o[8] = {a0 * inv, a1 * inv, a2 * inv, a3 * inv,
                      a4 * inv, a5 * inv, a6 * inv, a7 * inv};
        size_t base = (size_t)wid * 128 + l4 * 8;
        if (mode == 0) {
#pragma unroll
            for (int k = 0; k < 8; ++k) o[k] = o[k] > 0.f ? o[k] : expm1f(o[k]);
        } else {
            float4 r0 = *(const float4*)(resid + base);
            float4 r1 = *(const float4*)(resid + base + 4);
            o[0] += r0.x; o[1] += r0.y; o[2] += r0.z; o[3] += r0.w;
            o[4] += r1.x; o[5] += r1.y; o[6] += r1.z; o[7] += r1.w;
        }
        float4 w0 = {o[0], o[1], o[2], o[3]};
        float4 w1 = {o[4], o[5], o[6], o[7]};
        *(float4*)(out + base) = w0;
        *(float4*)(out + base + 4) = w1;
    }
}

// ---------------- launch ----------------

extern "C" void kernel_launch(void* const* d_in, const int* in_sizes, int n_in,
                              void* d_out, int out_size, void* d_ws, size_t ws_size,
                              hipStream_t stream) {
    const int N = in_sizes[0] / 128;
    const int E = in_sizes[2];

    const float* x      = (const float*)d_in[0];
    const int*   eidx   = (const int*)d_in[1];
    const float* ev     = (const float*)d_in[2];
    const float* encW   = (const float*)d_in[3];
    const float* encb   = (const float*)d_in[4];
    const float* Wstack = (const float*)d_in[5];
    const float* astack = (const float*)d_in[6];
    float* out = (float*)d_out;

    const int* row = eidx;
    const int* colv = eidx + E;

    const int NCH = (N + 255) / 256;   // 256-node chunks for monotonic scan

    char* p = (char*)d_ws;
    float* xc   = (float*)p; p += (size_t)N * 128 * 4;
    float* xcB  = (float*)p; p += (size_t)N * 128 * 4;
    unsigned short* hbf = (unsigned short*)p; p += (size_t)N * 128 * 2;
    float* asrc = (float*)p; p += (size_t)N * 8 * 4;
    float* adst = (float*)p; p += (size_t)N * 8 * 4;
    short8* Wh  = (short8*)p; p += 3 * 2048 * 16;
    short8* Wl  = (short8*)p; p += 3 * 2048 * 16;
    int2* csr_cv = (int2*)p; p += (size_t)E * 8;
    int* deg    = (int*)p;   p += (size_t)N * 4;     // 16B-aligned (all prior multiples of 16)
    int* rowptr = (int*)p;   p += (size_t)(N + 1) * 4;

    // rank/perm alias the xcB buffer: rank dead after sperm_gemm, perm dead
    // after gathercv; xcB first written by agg0 (after gathercv). Stream-ordered.
    // (NOT xc — encoder writes xc concurrently with scan in enc_scan_kernel.)
    int* rank = (int*)xcB;
    int* perm = rank + E;

    const int GB = (N + 63) / 64;
    const int AGG = (N + 3) / 4;   // 4 nodes (waves) per 256-thread block
    const int EB = (E + 255) / 256;

    // --- CSR build + weight pack (fused) ---
    hipMemsetAsync(deg, 0, (size_t)N * 4, stream);
    histpack_kernel<<<EB + 24, 256, 0, stream>>>(row, deg, rank, E, EB,
                                                 encW, Wstack, Wh, Wl);

    // --- encoder GEMM || monotonic degree scan ---
    enc_scan_kernel<<<GB + NCH, 256, 0, stream>>>(x, Wh, Wl, encb, xc, N, GB,
                                                  deg, rowptr);

    // --- layer-0 GEMM || scatterperm ---
    sperm_gemm_kernel<<<GB + EB, 256, 0, stream>>>(xc, Wh + 2048, Wl + 2048, astack,
                                                   hbf, asrc, adst, N, GB,
                                                   row, rank, rowptr, perm, E);

    // --- csr_cv fill (coalesced) ---
    gathercv_kernel<<<EB, 256, 0, stream>>>(perm, colv, ev, csr_cv, E);

    // --- layer 0 aggregate ---
    aggregate_kernel<<<AGG, 256, 0, stream>>>(rowptr, csr_cv, hbf, asrc, adst,
                                              nullptr, xcB, 0, N);

    // --- layer 1: h1 (bf16) + alpha1 ---
    gemm_mfma<<<GB, 256, 0, stream>>>(xcB, Wh + 4096, Wl + 4096, astack + 256,
                                      hbf, asrc, adst, N);
    aggregate_kernel<<<AGG, 256, 0, stream>>>(rowptr, csr_cv, hbf, asrc, adst,
                                              xcB, out, 1, N);
}